// Round 4
// baseline (197.280 us; speedup 1.0000x reference)
//
#include <hip/hip_runtime.h>
#include <hip/hip_bf16.h>

#define LSEQ 2048
#define BB   2048
#define TT   7
#define REC  52   // 49 matrix + scale + score + maskcnt (float), 208 B = 16B-aligned

#define SWZ(dst, src, imm) \
  dst = __int_as_float(__builtin_amdgcn_ds_swizzle(__float_as_int(src), imm))

// ---------------------------------------------------------------------------
// Kernel 1 (row-decomposed): 8 lanes per (batch, chunk) matrix.
// Lane s in [0,6] owns row s of M; lane 7 does gold-path score bookkeeping.
// Per step i: row <- (row . E) * ee, where ee[t] = exp(em[i][t]) is computed
// one-per-lane and broadcast via ds_swizzle within the 8-lane group.
// E = exp(transitions), selected by contagion flag, cached in registers.
// ---------------------------------------------------------------------------
template<int K>
__global__ __launch_bounds__(256, 4)
void crf_chunk_kernel(const float* __restrict__ em,
                      const int*   __restrict__ tags,
                      const int*   __restrict__ qmask,
                      const int*   __restrict__ mask,
                      const float* __restrict__ self_t,
                      const float* __restrict__ other_t,
                      float* __restrict__ recs) {
  constexpr int C = LSEQ / K;
  __shared__ __align__(16) float sE[2][REC];   // exp(transitions): [0]=self, [1]=other
  __shared__ __align__(16) float sT[2][REC];   // raw transitions (for gold-path score)
  int tid = threadIdx.x;
  if (tid < 49) {
    float sv = self_t[tid];
    float ov = other_t[tid];
    sE[0][tid] = expf(sv);
    sE[1][tid] = expf(ov);
    sT[0][tid] = sv;
    sT[1][tid] = ov;
  } else if (tid < REC) {
    sE[0][tid] = 0.f; sE[1][tid] = 0.f;
    sT[0][tid] = 0.f; sT[1][tid] = 0.f;
  }
  __syncthreads();

  int s = tid & 7;                       // lane within 8-lane group
  int g = blockIdx.x * 32 + (tid >> 3);  // global matrix id
  int b = g & (BB - 1);
  int c = g >> 11;                       // g / BB

  float row[TT];
#pragma unroll
  for (int t = 0; t < TT; ++t) row[t] = (s == t) ? 1.0f : 0.0f;  // lane 7: all-zero

  float sc = 0.0f;
  int   mc = 0;
  int i0    = c * C;
  int i_end = i0 + C;
  int tp = 0, qp;
  if (c == 0) {
    qp = qmask[b];
    if (s == 7) { mc = mask[b]; tp = tags[b]; }
    i0 = 1;                              // step 0 is the alpha-init (combine kernel)
  } else {
    qp = qmask[(size_t)(i0 - 1) * BB + b];
    if (s == 7) tp = tags[(size_t)(i0 - 1) * BB + b];
  }

  const float* em_p = em    + ((size_t)i0 * BB + b) * TT;   // group base
  const int*   qm_p = qmask + (size_t)i0 * BB + b;
  const int*   mk_p = mask  + (size_t)i0 * BB + b;
  const int*   tg_p = tags  + (size_t)i0 * BB + b;

  float Er[49];
  int contPrev = -1;                     // force initial load

  for (int i = i0; i < i_end; ++i) {
    float e = 0.f;
    if (s < 7) e = em_p[s];
    int qm = *qm_p;
    int mi = *mk_p;
    int cont = (qm != qp) ? 1 : 0;

    if (__any(cont != contPrev)) {
      const float4* p = reinterpret_cast<const float4*>(sE[cont]);
#pragma unroll
      for (int k2 = 0; k2 < 12; ++k2) {
        float4 v = p[k2];
        Er[4*k2+0] = v.x; Er[4*k2+1] = v.y; Er[4*k2+2] = v.z; Er[4*k2+3] = v.w;
      }
      Er[48] = sE[cont][48];
      contPrev = cont;
    }

    float ee = __expf(e);                // native v_exp: 2 instrs

    // broadcast ee across the 8-lane group: eb_[t] = ee from lane (base|t)
    // BitMode offset = (or_mask<<5) | and_mask(0x18)
    float eb_[7];
    SWZ(eb_[0], ee, 0x018);
    SWZ(eb_[1], ee, 0x038);
    SWZ(eb_[2], ee, 0x058);
    SWZ(eb_[3], ee, 0x078);
    SWZ(eb_[4], ee, 0x098);
    SWZ(eb_[5], ee, 0x0B8);
    SWZ(eb_[6], ee, 0x0D8);

    // gold-path score (lane 7 only; its row stays zero)
    if (s == 7) {
      int tg = *tg_p;
      float etag = em_p[tg];
      float ttag = sT[cont][tp * TT + tg];
      if (mi) { sc += ttag + etag; ++mc; }
      tp = tg;
    }
    qp = qm;

    // acc = row . E  (independent of ee -> overlaps swizzle latency)
    float a0 = 0.f, a1 = 0.f, a2 = 0.f, a3 = 0.f, a4 = 0.f, a5 = 0.f, a6 = 0.f;
#pragma unroll
    for (int r = 0; r < 7; ++r) {
      float mr = row[r];
      a0 = fmaf(mr, Er[r*7+0], a0);
      a1 = fmaf(mr, Er[r*7+1], a1);
      a2 = fmaf(mr, Er[r*7+2], a2);
      a3 = fmaf(mr, Er[r*7+3], a3);
      a4 = fmaf(mr, Er[r*7+4], a4);
      a5 = fmaf(mr, Er[r*7+5], a5);
      a6 = fmaf(mr, Er[r*7+6], a6);
    }
    if (__any(mi == 0)) {
      row[0] = mi ? a0 * eb_[0] : row[0];
      row[1] = mi ? a1 * eb_[1] : row[1];
      row[2] = mi ? a2 * eb_[2] : row[2];
      row[3] = mi ? a3 * eb_[3] : row[3];
      row[4] = mi ? a4 * eb_[4] : row[4];
      row[5] = mi ? a5 * eb_[5] : row[5];
      row[6] = mi ? a6 * eb_[6] : row[6];
    } else {
      row[0] = a0 * eb_[0]; row[1] = a1 * eb_[1]; row[2] = a2 * eb_[2];
      row[3] = a3 * eb_[3]; row[4] = a4 * eb_[4]; row[5] = a5 * eb_[5];
      row[6] = a6 * eb_[6];
    }

    em_p += (size_t)BB * TT;
    qm_p += BB; mk_p += BB; tg_p += BB;
  }

  // group-wide max (lane 7 contributes 0 -- harmless, real max > 0)
  float mx = row[0];
#pragma unroll
  for (int t = 1; t < TT; ++t) mx = fmaxf(mx, row[t]);
  {
    float v;
    SWZ(v, mx, 0x041F);  // xor 1
    mx = fmaxf(mx, v);
    SWZ(v, mx, 0x081F);  // xor 2
    mx = fmaxf(mx, v);
    SWZ(v, mx, 0x101F);  // xor 4
    mx = fmaxf(mx, v);
  }
  float inv = 1.0f / mx;

  float* rp = recs + ((size_t)c * BB + b) * REC;
  if (s < 7) {
#pragma unroll
    for (int t = 0; t < TT; ++t) rp[s * 7 + t] = row[t] * inv;
  } else {
    rp[49] = logf(mx);
    rp[50] = sc;
    rp[51] = (float)mc;
  }
}

// ---------------------------------------------------------------------------
// Kernel 2: one wave per batch; sequentially fold the K chunk operators into
// the alpha vector (exp-space, renormalized each step), then finish score/logZ.
// ---------------------------------------------------------------------------
__global__ __launch_bounds__(64)
void crf_combine_kernel(const float* __restrict__ recs,
                        const float* __restrict__ em,
                        const int*   __restrict__ tags,
                        const float* __restrict__ start_t,
                        const float* __restrict__ end_t,
                        float* __restrict__ results,
                        int K) {
  int b = blockIdx.x;
  int j = threadIdx.x;
  __shared__ float lds[REC];

  float al[TT];
#pragma unroll
  for (int t = 0; t < TT; ++t) al[t] = expf(start_t[t] + em[(size_t)b * TT + t]);

  float lacc = 0.f, sc = 0.f, mcf = 0.f;
  float r = (j < REC) ? recs[(size_t)b * REC + j] : 0.f;   // record (c=0, b)

  for (int c = 0; c < K; ++c) {
    if (j < REC) lds[j] = r;
    __syncthreads();
    if (c + 1 < K && j < REC)
      r = recs[((size_t)(c + 1) * BB + b) * REC + j];      // prefetch next

    float nt = 0.f;
    if (j < TT) {
#pragma unroll
      for (int s = 0; s < TT; ++s) nt = fmaf(al[s], lds[s * TT + j], nt);
    }
    float lc  = lds[49];
    float scc = lds[50];
    float mcc = lds[51];
    __syncthreads();

    float na[TT];
#pragma unroll
    for (int t = 0; t < TT; ++t) na[t] = __shfl(nt, t);
    float mx = na[0];
#pragma unroll
    for (int t = 1; t < TT; ++t) mx = fmaxf(mx, na[t]);
    float inv = 1.0f / mx;
#pragma unroll
    for (int t = 0; t < TT; ++t) al[t] = na[t] * inv;
    lacc += logf(mx) + lc;
    sc += scc; mcf += mcc;
  }

  if (j == 0) {
    float z = 0.f;
#pragma unroll
    for (int t = 0; t < TT; ++t) z += al[t] * expf(end_t[t]);
    float logZ = lacc + logf(z);
    int t0 = tags[b];
    float s0 = start_t[t0] + em[(size_t)b * TT + t0];
    int se = (int)mcf - 1;
    int te = tags[(size_t)se * BB + b];
    results[b] = (sc + s0 + end_t[te]) - logZ;
  }
}

// ---------------------------------------------------------------------------
// Kernel 3: deterministic tree-reduce of the 2048 per-batch results.
// ---------------------------------------------------------------------------
__global__ __launch_bounds__(256)
void crf_reduce_kernel(const float* __restrict__ results, float* __restrict__ out) {
  __shared__ float s[256];
  int t = threadIdx.x;
  float v = 0.f;
  for (int i = t; i < BB; i += 256) v += results[i];
  s[t] = v;
  __syncthreads();
  for (int off = 128; off > 0; off >>= 1) {
    if (t < off) s[t] += s[t + off];
    __syncthreads();
  }
  if (t == 0) out[0] = s[0];
}

extern "C" void kernel_launch(void* const* d_in, const int* in_sizes, int n_in,
                              void* d_out, int out_size, void* d_ws, size_t ws_size,
                              hipStream_t stream) {
  const float* em      = (const float*)d_in[0];
  const int*   tags    = (const int*)d_in[1];
  const int*   qmask   = (const int*)d_in[2];
  const int*   mask    = (const int*)d_in[3];
  const float* start_t = (const float*)d_in[4];
  const float* end_t   = (const float*)d_in[5];
  const float* self_t  = (const float*)d_in[6];
  const float* other_t = (const float*)d_in[7];

  float* recs = (float*)d_ws;

  // choose chunk count to fit workspace: K*B*REC*4 + B*4 bytes
  int K = 64;
  auto need = [](int k) { return (size_t)k * BB * REC * 4 + (size_t)BB * 4; };
  if      (ws_size >= need(64)) K = 64;
  else if (ws_size >= need(32)) K = 32;
  else if (ws_size >= need(16)) K = 16;
  else if (ws_size >= need(8))  K = 8;
  else                          K = 4;

  float* results = recs + (size_t)K * BB * REC;

  int threads = 256;
  int blocks = (K * BB) / 32;   // 32 matrices (8 lanes each) per 256-thread block
  switch (K) {
    case 64: crf_chunk_kernel<64><<<blocks, threads, 0, stream>>>(em, tags, qmask, mask, self_t, other_t, recs); break;
    case 32: crf_chunk_kernel<32><<<blocks, threads, 0, stream>>>(em, tags, qmask, mask, self_t, other_t, recs); break;
    case 16: crf_chunk_kernel<16><<<blocks, threads, 0, stream>>>(em, tags, qmask, mask, self_t, other_t, recs); break;
    case 8:  crf_chunk_kernel<8 ><<<blocks, threads, 0, stream>>>(em, tags, qmask, mask, self_t, other_t, recs); break;
    default: crf_chunk_kernel<4 ><<<blocks, threads, 0, stream>>>(em, tags, qmask, mask, self_t, other_t, recs); break;
  }

  crf_combine_kernel<<<BB, 64, 0, stream>>>(recs, em, tags, start_t, end_t, results, K);
  crf_reduce_kernel<<<1, 256, 0, stream>>>(results, (float*)d_out);
}